// Round 1
// 705.519 us; speedup vs baseline: 1.0617x; 1.0617x over previous
//
#include <hip/hip_runtime.h>
#include <hip/hip_bf16.h>

typedef _Float16 f16;
typedef _Float16 f16x8 __attribute__((ext_vector_type(8)));
typedef float f32x4 __attribute__((ext_vector_type(4)));

#define NB 8
#define NC 192
#define NC3 576
#define NS 16384
#define NHD 4

// ---- workspace offsets (bytes). total ~355 MB ----
#define OFF_X16   (0ll)
#define OFF_CN16  (50331648ll)     // reused as qkv1 part buffer after kernel A
#define OFF_CN1   (100663296ll)
#define OFF_CNF   (150994944ll)
#define OFF_QKVD  (201326592ll)
#define OFF_NORMS (352321536ll)
#define OFF_G1    (352346112ll)
#define OFF_G2    (352641024ll)
#define OFF_ZPAD  (352935936ll)
#define OFF_ATTN  (352936960ll)
#define OFF_W116  (353231872ll)
#define OFF_WQ16  (353305600ll)
#define OFF_W3P   (353526784ll)
#define OFF_MCOMB (354190336ll)
#define OFF_WDWT  (354780160ll)
// E-stage partials overlay the dead cn1 buffer [OFF_CN1, OFF_CN1+50MB)
#define OFF_G1P   (100663296ll)               // 8*4*32*2304*4 = 9437184
#define OFF_G2P   (110100480ll)               // 9437184
#define OFF_NPART (119537664ll)               // 8*32*192*4*4 = 786432

__device__ __forceinline__ void async16(const void* g, void* l) {
  __builtin_amdgcn_global_load_lds(
      (const __attribute__((address_space(1))) unsigned int*)g,
      (__attribute__((address_space(3))) unsigned int*)l, 16, 0, 0);
}
#define MFMA(a,b,c) __builtin_amdgcn_mfma_f32_16x16x32_f16((a),(b),(c),0,0,0)

// ---------------------------------------------------------------------------
// P2: cast/pack all weights to f16. w3 repacked [tap][co][ci]; wdw repacked+cast
// to wdwT[tap][gc] (f16) so k_dw can load 8 channels' weights as one 16B read.
__global__ void k_wcast(const float* __restrict__ w1, const float* __restrict__ wq,
                        const float* __restrict__ w3, const float* __restrict__ wdw,
                        f16* __restrict__ w1o, f16* __restrict__ wqo,
                        f16* __restrict__ w3p, f16* __restrict__ wdwT)
{
  int idx = blockIdx.x * 256 + threadIdx.x;              // 484416 total
  if (idx < 36864) {
    w1o[idx] = (f16)w1[idx];
  } else if (idx < 147456) {
    int i = idx - 36864;
    wqo[i] = (f16)wq[i];
  } else if (idx < 479232) {
    int i = idx - 147456;
    int tap = i / 36864;
    int rem = i % 36864;                                 // co*192+ci
    w3p[i] = (f16)w3[(size_t)rem * 9 + tap];
  } else if (idx < 484416) {
    int i = idx - 479232;                                // 5184 = 9*576
    int tap = i / 576;
    int gc = i % 576;
    wdwT[i] = (f16)wdw[(size_t)gc * 9 + tap];
  }
}

// ---------------------------------------------------------------------------
// P1: transpose-cast x,cn : fp32 [b][c][s] -> f16 [b][s][c]
__global__ __launch_bounds__(256)
void k_cast_t(const float* __restrict__ xin, const float* __restrict__ cnin,
              f16* __restrict__ xo, f16* __restrict__ cno)
{
  __shared__ f16 tile[64 * 66];
  int b = blockIdx.z & 7;
  const float* in = (blockIdx.z >= 8) ? cnin : xin;
  f16* out = (blockIdx.z >= 8) ? cno : xo;
  int s0 = blockIdx.x * 64, c0 = blockIdx.y * 64;
  int t = threadIdx.x;
  int sl = t & 63, cq = t >> 6;
#pragma unroll
  for (int r = 0; r < 16; ++r) {
    int cl = r * 4 + cq;
    float v = in[((size_t)b * NC + c0 + cl) * NS + s0 + sl];
    tile[cl * 66 + sl] = (f16)v;
  }
  __syncthreads();
  int cl2 = t & 63, sq = t >> 6;
#pragma unroll
  for (int r = 0; r < 16; ++r) {
    int sl2 = r * 4 + sq;
    out[((size_t)b * NS + s0 + sl2) * NC + c0 + cl2] = tile[cl2 * 66 + sl2];
  }
}

// ---------------------------------------------------------------------------
// BT-GEMM: out[b][s][co] = sum_ci act[b][s][ci] * wt[co][ci]. M=s tile 256, N=co 64, K=192.
__global__ __launch_bounds__(256, 2)
void k_gemm_act(const f16* __restrict__ act, const f16* __restrict__ wt,
                f16* __restrict__ out)
{
  __shared__ f16 At[256 * 32];
  __shared__ f16 Bt[64 * 32];
  const int tid = threadIdx.x;
  const int b = blockIdx.z;
  const int s0 = blockIdx.x * 256;
  const int n0 = blockIdx.y * 64;
  const int w = tid >> 6, lane = tid & 63, quad = lane >> 4, l16 = lane & 15;
  const f16* actB = act + (size_t)b * NS * NC;

  const f32x4 Z = {0.f, 0.f, 0.f, 0.f};
  f32x4 acc[4][4];
#pragma unroll
  for (int i = 0; i < 4; ++i)
#pragma unroll
    for (int j = 0; j < 4; ++j) acc[i][j] = Z;

  for (int kc = 0; kc < 6; ++kc) {
    const int k0 = kc * 32;
#pragma unroll
    for (int i = 0; i < 4; ++i) {
      int r = i * 64 + (w << 4) + (lane >> 2);
      int col = k0 + ((((lane & 3) + (r >> 2)) & 3) << 3);
      async16(actB + (size_t)(s0 + r) * NC + col, At + (size_t)(i * 64 + (w << 4)) * 32);
    }
    {
      int rb = (w << 4) + (lane >> 2);
      int colb = k0 + ((((lane & 3) + (rb >> 2)) & 3) << 3);
      async16(wt + (size_t)(n0 + rb) * NC + colb, Bt + (size_t)(w << 4) * 32);
    }
    __syncthreads();

    f16x8 bf[4];
#pragma unroll
    for (int nt = 0; nt < 4; ++nt) {
      int n = nt * 16 + l16;
      int p = (quad - (n >> 2)) & 3;
      bf[nt] = *(const f16x8*)(Bt + n * 32 + p * 8);
    }
#pragma unroll
    for (int mt = 0; mt < 4; ++mt) {
      int m = w * 64 + mt * 16 + l16;
      int p = (quad - (m >> 2)) & 3;
      f16x8 af = *(const f16x8*)(At + m * 32 + p * 8);
#pragma unroll
      for (int nt = 0; nt < 4; ++nt) acc[mt][nt] = MFMA(af, bf[nt], acc[mt][nt]);
    }
    __syncthreads();
  }
#pragma unroll
  for (int mt = 0; mt < 4; ++mt)
#pragma unroll
    for (int r = 0; r < 4; ++r) {
      int sg = s0 + w * 64 + mt * 16 + quad * 4 + r;
      f16* o = out + ((size_t)b * NS + sg) * NC + n0;
#pragma unroll
      for (int nt = 0; nt < 4; ++nt) o[nt * 16 + l16] = (f16)acc[mt][nt][r];
    }
}

// ---------------------------------------------------------------------------
// conv3x3 implicit GEMM, halo-staged: per block, 2 output image rows (256 s),
// 64 co. Per K-chunk of 32 ci: stage 4-row halo (y0-1..y0+2) x [pad|128|pad]
// once; all 9 taps read it at LDS offsets. Taps' B staged in 2 groups (5+4).
// 4 barriers/kc (was 18), 64-80 MFMA per barrier-pair (was 16).
__global__ __launch_bounds__(256, 2)
void k_conv3(const f16* __restrict__ act, const f16* __restrict__ w3p,
             f16* __restrict__ out, const f16* __restrict__ zpad)
{
  __shared__ f16 At[4 * 130 * 32];   // 33280 B: [row 0..3][xp 0..129][32ch] swizzled
  __shared__ f16 Bt[5 * 64 * 32];    // 20480 B: [tapslot][co][32ch] swizzled
  const int tid = threadIdx.x;
  // XCD-chunked bijective swizzle (1536 % 8 == 0): each XCD gets one batch's
  // 192 blocks; the 3 N-blocks + neighbor stiles sharing an A-panel co-reside.
  const int bid = blockIdx.x;                      // 0..1535
  const int swz = (bid & 7) * 192 + (bid >> 3);
  const int b = swz / 192;
  const int rem = swz % 192;                       // stile*3 + nblk
  const int stile = rem / 3;
  const int nblk = rem % 3;
  const int y0 = stile * 2;
  const int s0 = stile * 256;
  const int n0 = nblk * 64;
  const int w = tid >> 6, lane = tid & 63, quad = lane >> 4, l16 = lane & 15;
  const f16* actB = act + (size_t)b * NS * NC;

  // zero the xp=0 / xp=129 pad columns once (staging never writes them)
  {
    int pos = tid >> 5, ch = tid & 31;             // 8 pad positions x 32 ch
    At[((pos >> 1) * 130 + ((pos & 1) ? 129 : 0)) * 32 + ch] = (f16)0.f;
  }

  const f32x4 Z = {0.f, 0.f, 0.f, 0.f};
  f32x4 acc[4][4];
#pragma unroll
  for (int i = 0; i < 4; ++i)
#pragma unroll
    for (int j = 0; j < 4; ++j) acc[i][j] = Z;

  const int yrow = y0 - 1 + w;                     // wave-uniform halo row
  const bool rowok = ((unsigned)yrow < 128u);
  const f16* arow = actB + (size_t)(yrow * 128) * NC;

  for (int kc = 0; kc < 6; ++kc) {
    const int k0 = kc * 32;
    // ---- stage At: wave w stages halo row w (xp 1..128), swizzled source ----
#pragma unroll
    for (int i = 0; i < 8; ++i) {
      int x = i * 16 + (lane >> 2);
      int rs = w * 130 + 1 + x;                    // staged position index
      int gsrc = ((lane & 3) + (rs >> 2)) & 3;
      const f16* g = rowok ? (arow + (size_t)x * NC + k0 + gsrc * 8)
                           : (const f16*)zpad;
      async16(g, At + (w * 130 + 1) * 32 + i * 512);
    }
    // ---- stage Bt taps 0..4 ----
#pragma unroll
    for (int tp = 0; tp < 5; ++tp) {
      int co = (w << 4) + (lane >> 2);
      int gsrc = ((lane & 3) + (co >> 2)) & 3;
      async16(w3p + (size_t)tp * NC * NC + (size_t)(n0 + co) * NC + k0 + gsrc * 8,
              Bt + (tp * 64 + (w << 4)) * 32);
    }
    __syncthreads();
    // ---- compute taps 0..4 ----
#pragma unroll
    for (int tp = 0; tp < 5; ++tp) {
      const int dy = tp / 3 - 1, dx = tp % 3 - 1;
      f16x8 bf[4];
#pragma unroll
      for (int nt = 0; nt < 4; ++nt) {
        int n = nt * 16 + l16;
        int p = (quad - (n >> 2)) & 3;
        bf[nt] = *(const f16x8*)(Bt + (tp * 64 + n) * 32 + p * 8);
      }
#pragma unroll
      for (int mt = 0; mt < 4; ++mt) {
        int m = (w << 6) + mt * 16 + l16;
        int rr = ((m >> 7) + 1 + dy) * 130 + (m & 127) + 1 + dx;
        int p = (quad - (rr >> 2)) & 3;
        f16x8 af = *(const f16x8*)(At + rr * 32 + p * 8);
#pragma unroll
        for (int nt = 0; nt < 4; ++nt) acc[mt][nt] = MFMA(af, bf[nt], acc[mt][nt]);
      }
    }
    __syncthreads();
    // ---- stage Bt taps 5..8 into slots 0..3 ----
#pragma unroll
    for (int tp = 0; tp < 4; ++tp) {
      int co = (w << 4) + (lane >> 2);
      int gsrc = ((lane & 3) + (co >> 2)) & 3;
      async16(w3p + (size_t)(tp + 5) * NC * NC + (size_t)(n0 + co) * NC + k0 + gsrc * 8,
              Bt + (tp * 64 + (w << 4)) * 32);
    }
    __syncthreads();
    // ---- compute taps 5..8 ----
#pragma unroll
    for (int tp = 0; tp < 4; ++tp) {
      const int tap = tp + 5;
      const int dy = tap / 3 - 1, dx = tap % 3 - 1;
      f16x8 bf[4];
#pragma unroll
      for (int nt = 0; nt < 4; ++nt) {
        int n = nt * 16 + l16;
        int p = (quad - (n >> 2)) & 3;
        bf[nt] = *(const f16x8*)(Bt + (tp * 64 + n) * 32 + p * 8);
      }
#pragma unroll
      for (int mt = 0; mt < 4; ++mt) {
        int m = (w << 6) + mt * 16 + l16;
        int rr = ((m >> 7) + 1 + dy) * 130 + (m & 127) + 1 + dx;
        int p = (quad - (rr >> 2)) & 3;
        f16x8 af = *(const f16x8*)(At + rr * 32 + p * 8);
#pragma unroll
        for (int nt = 0; nt < 4; ++nt) acc[mt][nt] = MFMA(af, bf[nt], acc[mt][nt]);
      }
    }
    __syncthreads();
  }
#pragma unroll
  for (int mt = 0; mt < 4; ++mt)
#pragma unroll
    for (int r = 0; r < 4; ++r) {
      int sg = s0 + (w << 6) + mt * 16 + quad * 4 + r;
      f16* o = out + ((size_t)b * NS + sg) * NC + n0;
#pragma unroll
      for (int nt = 0; nt < 4; ++nt) o[nt * 16 + l16] = (f16)acc[mt][nt][r];
    }
}

// ---------------------------------------------------------------------------
// depthwise 3x3, 8-channel vectorized: one thread = 8 consecutive channels of one s.
__global__ __launch_bounds__(256)
void k_dw(const f16* __restrict__ in, const f16* __restrict__ wdwT,
          f16* __restrict__ out, int part)
{
  int idx = blockIdx.x * 256 + threadIdx.x;   // exact 3145728 = 8*16384*24
  int cg = idx % 24;
  int s = (idx / 24) % NS;
  int b = idx / (24 * NS);
  int x = s & 127, y = s >> 7;
  const f16* ip = in + ((size_t)b * NS + s) * NC + cg * 8;
  const f16* wp = wdwT + part * NC + cg * 8;
  float a[8] = {0.f, 0.f, 0.f, 0.f, 0.f, 0.f, 0.f, 0.f};
#pragma unroll
  for (int t = 0; t < 9; ++t) {
    int dy = t / 3 - 1, dx = t % 3 - 1;
    if (((unsigned)(x + dx) < 128u) && ((unsigned)(y + dy) < 128u)) {
      f16x8 v = *(const f16x8*)(ip + (dy * 128 + dx) * NC);
      f16x8 wv = *(const f16x8*)(wp + t * NC3);
#pragma unroll
      for (int j = 0; j < 8; ++j) a[j] += (float)wv[j] * (float)v[j];
    }
  }
  f16x8 o;
#pragma unroll
  for (int j = 0; j < 8; ++j) o[j] = (f16)a[j];
  *(f16x8*)(out + ((size_t)b * NS + s) * NC3 + part * NC + cg * 8) = o;
}

// ---------------------------------------------------------------------------
// E2 (fused with E1): per (b,h,split of 512 s): G1p = Q*K^T, G2p = CN*K^T partials
// via LDS-transpose + MFMA; per-channel stats (q2,k2,cn2,qc) from the same
// fragments, shfl-reduced across quads. NO ATOMICS.
__global__ __launch_bounds__(64)
void k_e2(const f16* __restrict__ qkvd, const f16* __restrict__ cnf,
          float* __restrict__ G1p, float* __restrict__ G2p,
          float* __restrict__ npart)
{
  __shared__ f16 qT[48 * 72];
  __shared__ f16 kT[48 * 72];
  __shared__ f16 cT[48 * 72];
  int blk = blockIdx.x;               // b(8) x h(4) x split(32)
  int split = blk & 31;
  int h = (blk >> 5) & 3;
  int b = blk >> 7;
  int lane = threadIdx.x, quad = lane >> 4, l16 = lane & 15;
  const f32x4 Z = {0.f, 0.f, 0.f, 0.f};
  f32x4 g1[3][3], g2[3][3];
#pragma unroll
  for (int i = 0; i < 3; ++i)
#pragma unroll
    for (int j = 0; j < 3; ++j) { g1[i][j] = Z; g2[i][j] = Z; }
  float q2[3] = {0.f, 0.f, 0.f}, k2[3] = {0.f, 0.f, 0.f};
  float cn2[3] = {0.f, 0.f, 0.f}, qc[3] = {0.f, 0.f, 0.f};

  int sBase = split * 512;
  for (int chunk = 0; chunk < 8; ++chunk) {
    int sb = sBase + chunk * 64;
    const f16* qrow = qkvd + ((size_t)b * NS + sb + lane) * NC3 + h * 48;
    const f16* crow = cnf + ((size_t)b * NS + sb + lane) * NC + h * 48;
    f16x8 qv[6], kv[6], nv[6];
#pragma unroll
    for (int i = 0; i < 6; ++i) {
      qv[i] = *(const f16x8*)(qrow + i * 8);
      kv[i] = *(const f16x8*)(qrow + 192 + i * 8);
      nv[i] = *(const f16x8*)(crow + i * 8);
    }
    __syncthreads();                 // previous iter's frag reads done
#pragma unroll
    for (int i = 0; i < 6; ++i)
#pragma unroll
      for (int j = 0; j < 8; ++j) {
        int c = i * 8 + j;
        qT[c * 72 + lane] = qv[i][j];
        kT[c * 72 + lane] = kv[i][j];
        cT[c * 72 + lane] = nv[i][j];
      }
    __syncthreads();
#pragma unroll
    for (int kk = 0; kk < 2; ++kk) {
      int ko = kk * 32 + quad * 8;
      f16x8 bfr[3];
#pragma unroll
      for (int dt = 0; dt < 3; ++dt) {
        bfr[dt] = *(const f16x8*)(kT + (dt * 16 + l16) * 72 + ko);
#pragma unroll
        for (int j = 0; j < 8; ++j) { float kf = (float)bfr[dt][j]; k2[dt] += kf * kf; }
      }
#pragma unroll
      for (int ct = 0; ct < 3; ++ct) {
        f16x8 aq = *(const f16x8*)(qT + (ct * 16 + l16) * 72 + ko);
        f16x8 an = *(const f16x8*)(cT + (ct * 16 + l16) * 72 + ko);
#pragma unroll
        for (int j = 0; j < 8; ++j) {
          float qf = (float)aq[j], nf = (float)an[j];
          q2[ct] += qf * qf; cn2[ct] += nf * nf; qc[ct] += qf * nf;
        }
#pragma unroll
        for (int dt = 0; dt < 3; ++dt) {
          g1[ct][dt] = MFMA(aq, bfr[dt], g1[ct][dt]);
          g2[ct][dt] = MFMA(an, bfr[dt], g2[ct][dt]);
        }
      }
    }
  }
  // G partial write (coalesced, no atomics)
  size_t gbase = ((size_t)((b * NHD + h) * 32 + split)) * 2304;
#pragma unroll
  for (int ct = 0; ct < 3; ++ct)
#pragma unroll
    for (int dt = 0; dt < 3; ++dt)
#pragma unroll
      for (int r = 0; r < 4; ++r) {
        int c = ct * 16 + quad * 4 + r;
        int d = dt * 16 + l16;
        G1p[gbase + c * 48 + d] = g1[ct][dt][r];
        G2p[gbase + c * 48 + d] = g2[ct][dt][r];
      }
  // stats: reduce across quads (lanes l16, l16+16, l16+32, l16+48)
#pragma unroll
  for (int t = 0; t < 3; ++t) {
    q2[t] += __shfl_xor(q2[t], 16, 64);  q2[t] += __shfl_xor(q2[t], 32, 64);
    k2[t] += __shfl_xor(k2[t], 16, 64);  k2[t] += __shfl_xor(k2[t], 32, 64);
    cn2[t] += __shfl_xor(cn2[t], 16, 64); cn2[t] += __shfl_xor(cn2[t], 32, 64);
    qc[t] += __shfl_xor(qc[t], 16, 64);  qc[t] += __shfl_xor(qc[t], 32, 64);
  }
  if (lane < 16) {
#pragma unroll
    for (int ct = 0; ct < 3; ++ct) {
      int c = h * 48 + ct * 16 + lane;
      float* np = npart + (((size_t)(b * 32 + split)) * NC + c) * 4;
      np[0] = q2[ct]; np[1] = k2[ct]; np[2] = cn2[ct]; np[3] = qc[ct];
    }
  }
}

// ---------------------------------------------------------------------------
// E1b: norms[b][c][4] = sum over 32 splits of npart. 6144 threads, coalesced.
__global__ void k_e1b(const float* __restrict__ npart, float* __restrict__ norms)
{
  int idx = blockIdx.x * 256 + threadIdx.x;    // 6144
  int b = idx / 768;
  int cs = idx % 768;                          // c*4 + stat
  const float* p = npart + (size_t)b * 32 * 768 + cs;
  float s = 0.f;
#pragma unroll
  for (int sp = 0; sp < 32; ++sp) s += p[sp * 768];
  norms[idx] = s;
}

// ---------------------------------------------------------------------------
// E2b: G[bh][c][d] = sum over 32 splits of partials. 294912 threads, coalesced.
__global__ void k_e2b(const float* __restrict__ G1p, const float* __restrict__ G2p,
                      float* __restrict__ G1, float* __restrict__ G2)
{
  int idx = blockIdx.x * 256 + threadIdx.x;    // 294912
  int bh = idx / 2304;
  int cd = idx % 2304;
  const float* p1 = G1p + ((size_t)bh * 32) * 2304 + cd;
  const float* p2 = G2p + ((size_t)bh * 32) * 2304 + cd;
  float s1 = 0.f, s2 = 0.f;
#pragma unroll
  for (int sp = 0; sp < 32; ++sp) { s1 += p1[sp * 2304]; s2 += p2[sp * 2304]; }
  G1[idx] = s1;
  G2[idx] = s2;
}

// ---------------------------------------------------------------------------
// F1: logits + softmax -> attn[b][h][c][d] (fp32)
__global__ __launch_bounds__(64)
void k_f1(const float* __restrict__ G1, const float* __restrict__ G2,
          const float* __restrict__ norms, const float* __restrict__ temp,
          float* __restrict__ attn)
{
  __shared__ float S[48 * 48];
  int h = blockIdx.x & 3, b = blockIdx.x >> 2;
  int t = threadIdx.x;
  float T = temp[h];
  const float EPS = 1e-12f;
#pragma unroll
  for (int i = 0; i < 36; ++i) {
    int idx = i * 64 + t;
    int c = idx / 48, d = idx % 48;
    const float* np = norms + ((size_t)b * NC + h * 48 + c) * 4;
    float q2 = np[0], cn2 = np[2], qc = np[3];
    float nq = fmaxf(sqrtf(q2), EPS);
    float ncn = fmaxf(sqrtf(cn2), EPS);
    float k2 = norms[((size_t)b * NC + h * 48 + d) * 4 + 1];
    float nk = fmaxf(sqrtf(k2), EPS);
    float ss = q2 / (nq * nq) + 2.f * qc / (nq * ncn) + cn2 / (ncn * ncn);
    float nsum = fmaxf(sqrtf(fmaxf(ss, 0.f)), EPS);
    size_t go = (((size_t)(b * NHD + h) * 48 + c) * 48 + d);
    S[idx] = (G1[go] / nq + G2[go] / ncn) / (nsum * nk) * T;
  }
  __syncthreads();
  if (t < 48) {
    float mx = -1e30f;
    for (int d = 0; d < 48; ++d) mx = fmaxf(mx, S[t * 48 + d]);
    float sum = 0.f;
    for (int d = 0; d < 48; ++d) { float e = expf(S[t * 48 + d] - mx); S[t * 48 + d] = e; sum += e; }
    float inv = 1.f / sum;
    float* ap = attn + (((size_t)(b * NHD + h) * 48 + t) * 48);
    for (int d = 0; d < 48; ++d) ap[d] = S[t * 48 + d] * inv;
  }
}

// ---------------------------------------------------------------------------
// F2: Mcomb[b][co][dg] = sum_cl projw[co][h*48+cl] * attn[b][h][cl][dg%48]  (f16 out)
__global__ void k_f2(const float* __restrict__ attn, const float* __restrict__ projw,
                     f16* __restrict__ mcomb)
{
  int idx = blockIdx.x * 256 + threadIdx.x;   // 294912 exact
  int dg = idx % NC;
  int co = (idx / NC) % NC;
  int b = idx / (NC * NC);
  int h = dg / 48, dl = dg % 48;
  const float* pw = projw + (size_t)co * NC + h * 48;
  const float* at = attn + ((size_t)(b * NHD + h) * 48) * 48 + dl;
  float a = 0.f;
#pragma unroll
  for (int cl = 0; cl < 48; ++cl) a += pw[cl] * at[cl * 48];
  mcomb[idx] = (f16)a;
}

// ---------------------------------------------------------------------------
// G: out[b][co][s] = sum_dg mcomb[b][co][dg] * v[b][s][dg], fp32 out
__global__ __launch_bounds__(256, 2)
void k_gemm_out(const f16* __restrict__ mcomb, const f16* __restrict__ qkvd,
                float* __restrict__ out)
{
  __shared__ f16 At[64 * 32];
  __shared__ f16 Bt[256 * 32];
  const int tid = threadIdx.x;
  const int b = blockIdx.z;
  const int s0 = blockIdx.x * 256;
  const int m0 = blockIdx.y * 64;
  const int w = tid >> 6, lane = tid & 63, quad = lane >> 4, l16 = lane & 15;
  const f16* mcB = mcomb + (size_t)b * NC * NC;
  const f16* vB = qkvd + (size_t)b * NS * NC3 + 384;

  const f32x4 Z = {0.f, 0.f, 0.f, 0.f};
  f32x4 acc[4][4];
#pragma unroll
  for (int i = 0; i < 4; ++i)
#pragma unroll
    for (int j = 0; j < 4; ++j) acc[i][j] = Z;

  for (int kc = 0; kc < 6; ++kc) {
    const int k0 = kc * 32;
    {
      int rb = (w << 4) + (lane >> 2);
      int colb = k0 + ((((lane & 3) + (rb >> 2)) & 3) << 3);
      async16(mcB + (size_t)(m0 + rb) * NC + colb, At + (size_t)(w << 4) * 32);
    }
#pragma unroll
    for (int i = 0; i < 4; ++i) {
      int r = i * 64 + (w << 4) + (lane >> 2);
      int col = k0 + ((((lane & 3) + (r >> 2)) & 3) << 3);
      async16(vB + (size_t)(s0 + r) * NC3 + col, Bt + (size_t)(i * 64 + (w << 4)) * 32);
    }
    __syncthreads();
    f16x8 af[4];
#pragma unroll
    for (int mt = 0; mt < 4; ++mt) {
      int m = mt * 16 + l16;
      int p = (quad - (m >> 2)) & 3;
      af[mt] = *(const f16x8*)(At + m * 32 + p * 8);
    }
#pragma unroll
    for (int nt = 0; nt < 4; ++nt) {
      int n = w * 64 + nt * 16 + l16;
      int p = (quad - (n >> 2)) & 3;
      f16x8 bf = *(const f16x8*)(Bt + n * 32 + p * 8);
#pragma unroll
      for (int mt = 0; mt < 4; ++mt) acc[mt][nt] = MFMA(af[mt], bf, acc[mt][nt]);
    }
    __syncthreads();
  }
#pragma unroll
  for (int mt = 0; mt < 4; ++mt)
#pragma unroll
    for (int r = 0; r < 4; ++r) {
      int cog = m0 + mt * 16 + quad * 4 + r;
      float* o = out + ((size_t)b * NC + cog) * NS + s0 + w * 64;
#pragma unroll
      for (int nt = 0; nt < 4; ++nt) o[nt * 16 + l16] = acc[mt][nt][r];
    }
}

// ---------------------------------------------------------------------------
extern "C" void kernel_launch(void* const* d_in, const int* in_sizes, int n_in,
                              void* d_out, int out_size, void* d_ws, size_t ws_size,
                              hipStream_t stream) {
  const float* x   = (const float*)d_in[0];
  const float* cn  = (const float*)d_in[1];
  const float* w1  = (const float*)d_in[2];
  const float* w3  = (const float*)d_in[3];
  const float* wq  = (const float*)d_in[4];
  const float* wdw = (const float*)d_in[5];
  const float* wpj = (const float*)d_in[6];
  const float* tmp = (const float*)d_in[7];
  float* out = (float*)d_out;
  char* ws = (char*)d_ws;

  f16* x16    = (f16*)(ws + OFF_X16);
  f16* cn16   = (f16*)(ws + OFF_CN16);
  f16* qkv1p  = (f16*)(ws + OFF_CN16);   // overlay: cn16 dead after kernel A
  f16* cn1    = (f16*)(ws + OFF_CN1);
  f16* cnf    = (f16*)(ws + OFF_CNF);
  f16* qkvd   = (f16*)(ws + OFF_QKVD);
  float* norms = (float*)(ws + OFF_NORMS);
  float* G1    = (float*)(ws + OFF_G1);
  float* G2    = (float*)(ws + OFF_G2);
  f16* zpad   = (f16*)(ws + OFF_ZPAD);
  float* attn  = (float*)(ws + OFF_ATTN);
  f16* w116   = (f16*)(ws + OFF_W116);
  f16* wq16   = (f16*)(ws + OFF_WQ16);
  f16* w3p    = (f16*)(ws + OFF_W3P);
  f16* mcomb  = (f16*)(ws + OFF_MCOMB);
  f16* wdwT   = (f16*)(ws + OFF_WDWT);
  float* G1p   = (float*)(ws + OFF_G1P);   // overlays dead cn1
  float* G2p   = (float*)(ws + OFF_G2P);
  float* npart = (float*)(ws + OFF_NPART);

  // zero page for conv3 edge lanes (ws is re-poisoned before every launch)
  hipMemsetAsync(ws + OFF_ZPAD, 0, 1024, stream);

  k_wcast<<<1893, 256, 0, stream>>>(w1, wq, w3, wdw, w116, wq16, w3p, wdwT);
  k_cast_t<<<dim3(256, 3, 16), 256, 0, stream>>>(x, cn, x16, cn16);
  k_gemm_act<<<dim3(64, 3, 8), 256, 0, stream>>>(cn16, w116, cn1);
  k_conv3<<<1536, 256, 0, stream>>>(cn1, w3p, cnf, zpad);
  for (int p = 0; p < 3; ++p) {
    k_gemm_act<<<dim3(64, 3, 8), 256, 0, stream>>>(x16, wq16 + p * 36864, qkv1p);
    k_dw<<<12288, 256, 0, stream>>>(qkv1p, wdwT, qkvd, p);
  }
  k_e2<<<1024, 64, 0, stream>>>(qkvd, cnf, G1p, G2p, npart);
  k_e1b<<<24, 256, 0, stream>>>(npart, norms);
  k_e2b<<<1152, 256, 0, stream>>>(G1p, G2p, G1, G2);
  k_f1<<<32, 64, 0, stream>>>(G1, G2, norms, tmp, attn);
  k_f2<<<1152, 256, 0, stream>>>(attn, wpj, mcomb);
  k_gemm_out<<<dim3(64, 3, 8), 256, 0, stream>>>(mcomb, qkvd, out);

  (void)in_sizes; (void)n_in; (void)out_size; (void)ws_size;
}

// Round 2
// 705.257 us; speedup vs baseline: 1.0621x; 1.0004x over previous
//
#include <hip/hip_runtime.h>
#include <hip/hip_bf16.h>

typedef _Float16 f16;
typedef _Float16 f16x4 __attribute__((ext_vector_type(4)));
typedef _Float16 f16x8 __attribute__((ext_vector_type(8)));
typedef float f32x4 __attribute__((ext_vector_type(4)));

#define NB 8
#define NC 192
#define NC3 576
#define NS 16384
#define NHD 4

// ---- workspace offsets (bytes). total ~355 MB ----
#define OFF_X16   (0ll)
#define OFF_CN16  (50331648ll)     // reused as qkv1 part buffer after kernel A
#define OFF_CN1   (100663296ll)
#define OFF_CNF   (150994944ll)
#define OFF_QKVD  (201326592ll)
#define OFF_NORMS (352321536ll)
#define OFF_G1    (352346112ll)
#define OFF_G2    (352641024ll)
#define OFF_ZPAD  (352935936ll)
#define OFF_ATTN  (352936960ll)
#define OFF_W116  (353231872ll)
#define OFF_WQ16  (353305600ll)
#define OFF_W3P   (353526784ll)
#define OFF_MCOMB (354190336ll)
#define OFF_WDWT  (354780160ll)
// E-stage partials overlay the dead cn1 buffer [OFF_CN1, OFF_CN1+50MB)
#define OFF_G1P   (100663296ll)               // 8*4*32*2304*4 = 9437184
#define OFF_G2P   (110100480ll)               // 9437184
#define OFF_NPART (119537664ll)               // 8*32*192*4*4 = 786432

__device__ __forceinline__ void async16(const void* g, void* l) {
  __builtin_amdgcn_global_load_lds(
      (const __attribute__((address_space(1))) unsigned int*)g,
      (__attribute__((address_space(3))) unsigned int*)l, 16, 0, 0);
}
#define MFMA(a,b,c) __builtin_amdgcn_mfma_f32_16x16x32_f16((a),(b),(c),0,0,0)

// ---------------------------------------------------------------------------
// P2: cast/pack all weights to f16. w3 repacked [tap][co][ci]; wdw repacked+cast
// to wdwT[tap][gc] (f16) so k_dw can load 8 channels' weights as one 16B read.
__global__ void k_wcast(const float* __restrict__ w1, const float* __restrict__ wq,
                        const float* __restrict__ w3, const float* __restrict__ wdw,
                        f16* __restrict__ w1o, f16* __restrict__ wqo,
                        f16* __restrict__ w3p, f16* __restrict__ wdwT)
{
  int idx = blockIdx.x * 256 + threadIdx.x;              // 484416 total
  if (idx < 36864) {
    w1o[idx] = (f16)w1[idx];
  } else if (idx < 147456) {
    int i = idx - 36864;
    wqo[i] = (f16)wq[i];
  } else if (idx < 479232) {
    int i = idx - 147456;
    int tap = i / 36864;
    int rem = i % 36864;                                 // co*192+ci
    w3p[i] = (f16)w3[(size_t)rem * 9 + tap];
  } else if (idx < 484416) {
    int i = idx - 479232;                                // 5184 = 9*576
    int tap = i / 576;
    int gc = i % 576;
    wdwT[i] = (f16)wdw[(size_t)gc * 9 + tap];
  }
}

// ---------------------------------------------------------------------------
// P1: transpose-cast x,cn : fp32 [b][c][s] -> f16 [b][s][c]
// Vectorized: 4x4 in-register sub-block transpose. float4 loads (16B),
// f16x4 LDS writes (8B), f16x8 LDS reads (16B, conflict-free @ STR=72),
// f16x8 global stores (16B).
#define TSTR 72
__global__ __launch_bounds__(256)
void k_cast_t(const float* __restrict__ xin, const float* __restrict__ cnin,
              f16* __restrict__ xo, f16* __restrict__ cno)
{
  __shared__ f16 tile[64 * TSTR];    // [s][c], 9216 B
  int b = blockIdx.z & 7;
  const float* in = (blockIdx.z >= 8) ? cnin : xin;
  f16* out = (blockIdx.z >= 8) ? cno : xo;
  int s0 = blockIdx.x * 64, c0 = blockIdx.y * 64;
  int t = threadIdx.x;
  int sb = t & 15, cb = t >> 4;      // 4-s chunk, 4-c chunk

  const float* ip = in + ((size_t)b * NC + c0 + cb * 4) * NS + s0 + sb * 4;
  f32x4 r0 = *(const f32x4*)(ip);
  f32x4 r1 = *(const f32x4*)(ip + NS);
  f32x4 r2 = *(const f32x4*)(ip + 2 * NS);
  f32x4 r3 = *(const f32x4*)(ip + 3 * NS);
#pragma unroll
  for (int j = 0; j < 4; ++j) {
    f16x4 p = { (f16)r0[j], (f16)r1[j], (f16)r2[j], (f16)r3[j] };
    *(f16x4*)(&tile[(sb * 4 + j) * TSTR + cb * 4]) = p;
  }
  __syncthreads();
  f16* op = out + ((size_t)b * NS + s0) * NC + c0;
#pragma unroll
  for (int it = 0; it < 2; ++it) {
    int g = t + it * 256;
    int s = g >> 3, k = g & 7;       // 8 lanes cover one 128B output row-chunk
    *(f16x8*)(op + (size_t)s * NC + k * 8) = *(const f16x8*)(&tile[s * TSTR + k * 8]);
  }
}

// ---------------------------------------------------------------------------
// BT-GEMM: out[b][s][co] = sum_ci act[b][s][ci] * wt[co][ci]. M=s tile 256, N=co 64, K=192.
__global__ __launch_bounds__(256, 2)
void k_gemm_act(const f16* __restrict__ act, const f16* __restrict__ wt,
                f16* __restrict__ out)
{
  __shared__ f16 At[256 * 32];
  __shared__ f16 Bt[64 * 32];
  const int tid = threadIdx.x;
  const int b = blockIdx.z;
  const int s0 = blockIdx.x * 256;
  const int n0 = blockIdx.y * 64;
  const int w = tid >> 6, lane = tid & 63, quad = lane >> 4, l16 = lane & 15;
  const f16* actB = act + (size_t)b * NS * NC;

  const f32x4 Z = {0.f, 0.f, 0.f, 0.f};
  f32x4 acc[4][4];
#pragma unroll
  for (int i = 0; i < 4; ++i)
#pragma unroll
    for (int j = 0; j < 4; ++j) acc[i][j] = Z;

  for (int kc = 0; kc < 6; ++kc) {
    const int k0 = kc * 32;
#pragma unroll
    for (int i = 0; i < 4; ++i) {
      int r = i * 64 + (w << 4) + (lane >> 2);
      int col = k0 + ((((lane & 3) + (r >> 2)) & 3) << 3);
      async16(actB + (size_t)(s0 + r) * NC + col, At + (size_t)(i * 64 + (w << 4)) * 32);
    }
    {
      int rb = (w << 4) + (lane >> 2);
      int colb = k0 + ((((lane & 3) + (rb >> 2)) & 3) << 3);
      async16(wt + (size_t)(n0 + rb) * NC + colb, Bt + (size_t)(w << 4) * 32);
    }
    __syncthreads();

    f16x8 bf[4];
#pragma unroll
    for (int nt = 0; nt < 4; ++nt) {
      int n = nt * 16 + l16;
      int p = (quad - (n >> 2)) & 3;
      bf[nt] = *(const f16x8*)(Bt + n * 32 + p * 8);
    }
#pragma unroll
    for (int mt = 0; mt < 4; ++mt) {
      int m = w * 64 + mt * 16 + l16;
      int p = (quad - (m >> 2)) & 3;
      f16x8 af = *(const f16x8*)(At + m * 32 + p * 8);
#pragma unroll
      for (int nt = 0; nt < 4; ++nt) acc[mt][nt] = MFMA(af, bf[nt], acc[mt][nt]);
    }
    __syncthreads();
  }
#pragma unroll
  for (int mt = 0; mt < 4; ++mt)
#pragma unroll
    for (int r = 0; r < 4; ++r) {
      int sg = s0 + w * 64 + mt * 16 + quad * 4 + r;
      f16* o = out + ((size_t)b * NS + sg) * NC + n0;
#pragma unroll
      for (int nt = 0; nt < 4; ++nt) o[nt * 16 + l16] = (f16)acc[mt][nt][r];
    }
}

// ---------------------------------------------------------------------------
// conv3x3 implicit GEMM, halo-staged: per block, 2 output image rows (256 s),
// 64 co. Per K-chunk of 32 ci: stage 4-row halo (y0-1..y0+2) x [pad|128|pad]
// once; all 9 taps read it at LDS offsets. Taps' B staged in 2 groups (5+4).
__global__ __launch_bounds__(256, 2)
void k_conv3(const f16* __restrict__ act, const f16* __restrict__ w3p,
             f16* __restrict__ out, const f16* __restrict__ zpad)
{
  __shared__ f16 At[4 * 130 * 32];   // 33280 B: [row 0..3][xp 0..129][32ch] swizzled
  __shared__ f16 Bt[5 * 64 * 32];    // 20480 B: [tapslot][co][32ch] swizzled
  const int tid = threadIdx.x;
  // XCD-chunked bijective swizzle (1536 % 8 == 0)
  const int bid = blockIdx.x;                      // 0..1535
  const int swz = (bid & 7) * 192 + (bid >> 3);
  const int b = swz / 192;
  const int rem = swz % 192;                       // stile*3 + nblk
  const int stile = rem / 3;
  const int nblk = rem % 3;
  const int y0 = stile * 2;
  const int s0 = stile * 256;
  const int n0 = nblk * 64;
  const int w = tid >> 6, lane = tid & 63, quad = lane >> 4, l16 = lane & 15;
  const f16* actB = act + (size_t)b * NS * NC;

  // zero the xp=0 / xp=129 pad columns once (staging never writes them)
  {
    int pos = tid >> 5, ch = tid & 31;             // 8 pad positions x 32 ch
    At[((pos >> 1) * 130 + ((pos & 1) ? 129 : 0)) * 32 + ch] = (f16)0.f;
  }

  const f32x4 Z = {0.f, 0.f, 0.f, 0.f};
  f32x4 acc[4][4];
#pragma unroll
  for (int i = 0; i < 4; ++i)
#pragma unroll
    for (int j = 0; j < 4; ++j) acc[i][j] = Z;

  const int yrow = y0 - 1 + w;                     // wave-uniform halo row
  const bool rowok = ((unsigned)yrow < 128u);
  const f16* arow = actB + (size_t)(yrow * 128) * NC;

  for (int kc = 0; kc < 6; ++kc) {
    const int k0 = kc * 32;
    // ---- stage At: wave w stages halo row w (xp 1..128), swizzled source ----
#pragma unroll
    for (int i = 0; i < 8; ++i) {
      int x = i * 16 + (lane >> 2);
      int rs = w * 130 + 1 + x;                    // staged position index
      int gsrc = ((lane & 3) + (rs >> 2)) & 3;
      const f16* g = rowok ? (arow + (size_t)x * NC + k0 + gsrc * 8)
                           : (const f16*)zpad;
      async16(g, At + (w * 130 + 1) * 32 + i * 512);
    }
    // ---- stage Bt taps 0..4 ----
#pragma unroll
    for (int tp = 0; tp < 5; ++tp) {
      int co = (w << 4) + (lane >> 2);
      int gsrc = ((lane & 3) + (co >> 2)) & 3;
      async16(w3p + (size_t)tp * NC * NC + (size_t)(n0 + co) * NC + k0 + gsrc * 8,
              Bt + (tp * 64 + (w << 4)) * 32);
    }
    __syncthreads();
    // ---- compute taps 0..4 ----
#pragma unroll
    for (int tp = 0; tp < 5; ++tp) {
      const int dy = tp / 3 - 1, dx = tp % 3 - 1;
      f16x8 bf[4];
#pragma unroll
      for (int nt = 0; nt < 4; ++nt) {
        int n = nt * 16 + l16;
        int p = (quad - (n >> 2)) & 3;
        bf[nt] = *(const f16x8*)(Bt + (tp * 64 + n) * 32 + p * 8);
      }
#pragma unroll
      for (int mt = 0; mt < 4; ++mt) {
        int m = (w << 6) + mt * 16 + l16;
        int rr = ((m >> 7) + 1 + dy) * 130 + (m & 127) + 1 + dx;
        int p = (quad - (rr >> 2)) & 3;
        f16x8 af = *(const f16x8*)(At + rr * 32 + p * 8);
#pragma unroll
        for (int nt = 0; nt < 4; ++nt) acc[mt][nt] = MFMA(af, bf[nt], acc[mt][nt]);
      }
    }
    __syncthreads();
    // ---- stage Bt taps 5..8 into slots 0..3 ----
#pragma unroll
    for (int tp = 0; tp < 4; ++tp) {
      int co = (w << 4) + (lane >> 2);
      int gsrc = ((lane & 3) + (co >> 2)) & 3;
      async16(w3p + (size_t)(tp + 5) * NC * NC + (size_t)(n0 + co) * NC + k0 + gsrc * 8,
              Bt + (tp * 64 + (w << 4)) * 32);
    }
    __syncthreads();
    // ---- compute taps 5..8 ----
#pragma unroll
    for (int tp = 0; tp < 4; ++tp) {
      const int tap = tp + 5;
      const int dy = tap / 3 - 1, dx = tap % 3 - 1;
      f16x8 bf[4];
#pragma unroll
      for (int nt = 0; nt < 4; ++nt) {
        int n = nt * 16 + l16;
        int p = (quad - (n >> 2)) & 3;
        bf[nt] = *(const f16x8*)(Bt + (tp * 64 + n) * 32 + p * 8);
      }
#pragma unroll
      for (int mt = 0; mt < 4; ++mt) {
        int m = (w << 6) + mt * 16 + l16;
        int rr = ((m >> 7) + 1 + dy) * 130 + (m & 127) + 1 + dx;
        int p = (quad - (rr >> 2)) & 3;
        f16x8 af = *(const f16x8*)(At + rr * 32 + p * 8);
#pragma unroll
        for (int nt = 0; nt < 4; ++nt) acc[mt][nt] = MFMA(af, bf[nt], acc[mt][nt]);
      }
    }
    __syncthreads();
  }
#pragma unroll
  for (int mt = 0; mt < 4; ++mt)
#pragma unroll
    for (int r = 0; r < 4; ++r) {
      int sg = s0 + (w << 6) + mt * 16 + quad * 4 + r;
      f16* o = out + ((size_t)b * NS + sg) * NC + n0;
#pragma unroll
      for (int nt = 0; nt < 4; ++nt) o[nt * 16 + l16] = (f16)acc[mt][nt][r];
    }
}

// ---------------------------------------------------------------------------
// depthwise 3x3, 8-channel vectorized: one thread = 8 consecutive channels of one s.
__global__ __launch_bounds__(256)
void k_dw(const f16* __restrict__ in, const f16* __restrict__ wdwT,
          f16* __restrict__ out, int part)
{
  int idx = blockIdx.x * 256 + threadIdx.x;   // exact 3145728 = 8*16384*24
  int cg = idx % 24;
  int s = (idx / 24) % NS;
  int b = idx / (24 * NS);
  int x = s & 127, y = s >> 7;
  const f16* ip = in + ((size_t)b * NS + s) * NC + cg * 8;
  const f16* wp = wdwT + part * NC + cg * 8;
  float a[8] = {0.f, 0.f, 0.f, 0.f, 0.f, 0.f, 0.f, 0.f};
#pragma unroll
  for (int t = 0; t < 9; ++t) {
    int dy = t / 3 - 1, dx = t % 3 - 1;
    if (((unsigned)(x + dx) < 128u) && ((unsigned)(y + dy) < 128u)) {
      f16x8 v = *(const f16x8*)(ip + (dy * 128 + dx) * NC);
      f16x8 wv = *(const f16x8*)(wp + t * NC3);
#pragma unroll
      for (int j = 0; j < 8; ++j) a[j] += (float)wv[j] * (float)v[j];
    }
  }
  f16x8 o;
#pragma unroll
  for (int j = 0; j < 8; ++j) o[j] = (f16)a[j];
  *(f16x8*)(out + ((size_t)b * NS + s) * NC3 + part * NC + cg * 8) = o;
}

// ---------------------------------------------------------------------------
// E2 (fused with E1): per (b,h,split of 512 s): G1p = Q*K^T, G2p = CN*K^T partials
// via LDS-transpose + MFMA; per-channel stats (q2,k2,cn2,qc) from the same
// fragments, shfl-reduced across quads. NO ATOMICS.
__global__ __launch_bounds__(64)
void k_e2(const f16* __restrict__ qkvd, const f16* __restrict__ cnf,
          float* __restrict__ G1p, float* __restrict__ G2p,
          float* __restrict__ npart)
{
  __shared__ f16 qT[48 * 72];
  __shared__ f16 kT[48 * 72];
  __shared__ f16 cT[48 * 72];
  int blk = blockIdx.x;               // b(8) x h(4) x split(32)
  int split = blk & 31;
  int h = (blk >> 5) & 3;
  int b = blk >> 7;
  int lane = threadIdx.x, quad = lane >> 4, l16 = lane & 15;
  const f32x4 Z = {0.f, 0.f, 0.f, 0.f};
  f32x4 g1[3][3], g2[3][3];
#pragma unroll
  for (int i = 0; i < 3; ++i)
#pragma unroll
    for (int j = 0; j < 3; ++j) { g1[i][j] = Z; g2[i][j] = Z; }
  float q2[3] = {0.f, 0.f, 0.f}, k2[3] = {0.f, 0.f, 0.f};
  float cn2[3] = {0.f, 0.f, 0.f}, qc[3] = {0.f, 0.f, 0.f};

  int sBase = split * 512;
  for (int chunk = 0; chunk < 8; ++chunk) {
    int sb = sBase + chunk * 64;
    const f16* qrow = qkvd + ((size_t)b * NS + sb + lane) * NC3 + h * 48;
    const f16* crow = cnf + ((size_t)b * NS + sb + lane) * NC + h * 48;
    f16x8 qv[6], kv[6], nv[6];
#pragma unroll
    for (int i = 0; i < 6; ++i) {
      qv[i] = *(const f16x8*)(qrow + i * 8);
      kv[i] = *(const f16x8*)(qrow + 192 + i * 8);
      nv[i] = *(const f16x8*)(crow + i * 8);
    }
    __syncthreads();                 // previous iter's frag reads done
#pragma unroll
    for (int i = 0; i < 6; ++i)
#pragma unroll
      for (int j = 0; j < 8; ++j) {
        int c = i * 8 + j;
        qT[c * 72 + lane] = qv[i][j];
        kT[c * 72 + lane] = kv[i][j];
        cT[c * 72 + lane] = nv[i][j];
      }
    __syncthreads();
#pragma unroll
    for (int kk = 0; kk < 2; ++kk) {
      int ko = kk * 32 + quad * 8;
      f16x8 bfr[3];
#pragma unroll
      for (int dt = 0; dt < 3; ++dt) {
        bfr[dt] = *(const f16x8*)(kT + (dt * 16 + l16) * 72 + ko);
#pragma unroll
        for (int j = 0; j < 8; ++j) { float kf = (float)bfr[dt][j]; k2[dt] += kf * kf; }
      }
#pragma unroll
      for (int ct = 0; ct < 3; ++ct) {
        f16x8 aq = *(const f16x8*)(qT + (ct * 16 + l16) * 72 + ko);
        f16x8 an = *(const f16x8*)(cT + (ct * 16 + l16) * 72 + ko);
#pragma unroll
        for (int j = 0; j < 8; ++j) {
          float qf = (float)aq[j], nf = (float)an[j];
          q2[ct] += qf * qf; cn2[ct] += nf * nf; qc[ct] += qf * nf;
        }
#pragma unroll
        for (int dt = 0; dt < 3; ++dt) {
          g1[ct][dt] = MFMA(aq, bfr[dt], g1[ct][dt]);
          g2[ct][dt] = MFMA(an, bfr[dt], g2[ct][dt]);
        }
      }
    }
  }
  // G partial write (coalesced, no atomics)
  size_t gbase = ((size_t)((b * NHD + h) * 32 + split)) * 2304;
#pragma unroll
  for (int ct = 0; ct < 3; ++ct)
#pragma unroll
    for (int dt = 0; dt < 3; ++dt)
#pragma unroll
      for (int r = 0; r < 4; ++r) {
        int c = ct * 16 + quad * 4 + r;
        int d = dt * 16 + l16;
        G1p[gbase + c * 48 + d] = g1[ct][dt][r];
        G2p[gbase + c * 48 + d] = g2[ct][dt][r];
      }
  // stats: reduce across quads (lanes l16, l16+16, l16+32, l16+48)
#pragma unroll
  for (int t = 0; t < 3; ++t) {
    q2[t] += __shfl_xor(q2[t], 16, 64);  q2[t] += __shfl_xor(q2[t], 32, 64);
    k2[t] += __shfl_xor(k2[t], 16, 64);  k2[t] += __shfl_xor(k2[t], 32, 64);
    cn2[t] += __shfl_xor(cn2[t], 16, 64); cn2[t] += __shfl_xor(cn2[t], 32, 64);
    qc[t] += __shfl_xor(qc[t], 16, 64);  qc[t] += __shfl_xor(qc[t], 32, 64);
  }
  if (lane < 16) {
#pragma unroll
    for (int ct = 0; ct < 3; ++ct) {
      int c = h * 48 + ct * 16 + lane;
      float* np = npart + (((size_t)(b * 32 + split)) * NC + c) * 4;
      np[0] = q2[ct]; np[1] = k2[ct]; np[2] = cn2[ct]; np[3] = qc[ct];
    }
  }
}

// ---------------------------------------------------------------------------
// E1b: norms[b][c][4] = sum over 32 splits of npart. 6144 threads, coalesced.
__global__ void k_e1b(const float* __restrict__ npart, float* __restrict__ norms)
{
  int idx = blockIdx.x * 256 + threadIdx.x;    // 6144
  int b = idx / 768;
  int cs = idx % 768;                          // c*4 + stat
  const float* p = npart + (size_t)b * 32 * 768 + cs;
  float s = 0.f;
#pragma unroll
  for (int sp = 0; sp < 32; ++sp) s += p[sp * 768];
  norms[idx] = s;
}

// ---------------------------------------------------------------------------
// E2b: G[bh][c][d] = sum over 32 splits of partials. 294912 threads, coalesced.
__global__ void k_e2b(const float* __restrict__ G1p, const float* __restrict__ G2p,
                      float* __restrict__ G1, float* __restrict__ G2)
{
  int idx = blockIdx.x * 256 + threadIdx.x;    // 294912
  int bh = idx / 2304;
  int cd = idx % 2304;
  const float* p1 = G1p + ((size_t)bh * 32) * 2304 + cd;
  const float* p2 = G2p + ((size_t)bh * 32) * 2304 + cd;
  float s1 = 0.f, s2 = 0.f;
#pragma unroll
  for (int sp = 0; sp < 32; ++sp) { s1 += p1[sp * 2304]; s2 += p2[sp * 2304]; }
  G1[idx] = s1;
  G2[idx] = s2;
}

// ---------------------------------------------------------------------------
// F1: logits + softmax -> attn[b][h][c][d] (fp32)
__global__ __launch_bounds__(64)
void k_f1(const float* __restrict__ G1, const float* __restrict__ G2,
          const float* __restrict__ norms, const float* __restrict__ temp,
          float* __restrict__ attn)
{
  __shared__ float S[48 * 48];
  int h = blockIdx.x & 3, b = blockIdx.x >> 2;
  int t = threadIdx.x;
  float T = temp[h];
  const float EPS = 1e-12f;
#pragma unroll
  for (int i = 0; i < 36; ++i) {
    int idx = i * 64 + t;
    int c = idx / 48, d = idx % 48;
    const float* np = norms + ((size_t)b * NC + h * 48 + c) * 4;
    float q2 = np[0], cn2 = np[2], qc = np[3];
    float nq = fmaxf(sqrtf(q2), EPS);
    float ncn = fmaxf(sqrtf(cn2), EPS);
    float k2 = norms[((size_t)b * NC + h * 48 + d) * 4 + 1];
    float nk = fmaxf(sqrtf(k2), EPS);
    float ss = q2 / (nq * nq) + 2.f * qc / (nq * ncn) + cn2 / (ncn * ncn);
    float nsum = fmaxf(sqrtf(fmaxf(ss, 0.f)), EPS);
    size_t go = (((size_t)(b * NHD + h) * 48 + c) * 48 + d);
    S[idx] = (G1[go] / nq + G2[go] / ncn) / (nsum * nk) * T;
  }
  __syncthreads();
  if (t < 48) {
    float mx = -1e30f;
    for (int d = 0; d < 48; ++d) mx = fmaxf(mx, S[t * 48 + d]);
    float sum = 0.f;
    for (int d = 0; d < 48; ++d) { float e = expf(S[t * 48 + d] - mx); S[t * 48 + d] = e; sum += e; }
    float inv = 1.f / sum;
    float* ap = attn + (((size_t)(b * NHD + h) * 48 + t) * 48);
    for (int d = 0; d < 48; ++d) ap[d] = S[t * 48 + d] * inv;
  }
}

// ---------------------------------------------------------------------------
// F2: Mcomb[b][co][dg] = sum_cl projw[co][h*48+cl] * attn[b][h][cl][dg%48]  (f16 out)
__global__ void k_f2(const float* __restrict__ attn, const float* __restrict__ projw,
                     f16* __restrict__ mcomb)
{
  int idx = blockIdx.x * 256 + threadIdx.x;   // 294912 exact
  int dg = idx % NC;
  int co = (idx / NC) % NC;
  int b = idx / (NC * NC);
  int h = dg / 48, dl = dg % 48;
  const float* pw = projw + (size_t)co * NC + h * 48;
  const float* at = attn + ((size_t)(b * NHD + h) * 48) * 48 + dl;
  float a = 0.f;
#pragma unroll
  for (int cl = 0; cl < 48; ++cl) a += pw[cl] * at[cl * 48];
  mcomb[idx] = (f16)a;
}

// ---------------------------------------------------------------------------
// G: out[b][co][s] = sum_dg mcomb[b][co][dg] * v[b][s][dg], fp32 out
__global__ __launch_bounds__(256, 2)
void k_gemm_out(const f16* __restrict__ mcomb, const f16* __restrict__ qkvd,
                float* __restrict__ out)
{
  __shared__ f16 At[64 * 32];
  __shared__ f16 Bt[256 * 32];
  const int tid = threadIdx.x;
  const int b = blockIdx.z;
  const int s0 = blockIdx.x * 256;
  const int m0 = blockIdx.y * 64;
  const int w = tid >> 6, lane = tid & 63, quad = lane >> 4, l16 = lane & 15;
  const f16* mcB = mcomb + (size_t)b * NC * NC;
  const f16* vB = qkvd + (size_t)b * NS * NC3 + 384;

  const f32x4 Z = {0.f, 0.f, 0.f, 0.f};
  f32x4 acc[4][4];
#pragma unroll
  for (int i = 0; i < 4; ++i)
#pragma unroll
    for (int j = 0; j < 4; ++j) acc[i][j] = Z;

  for (int kc = 0; kc < 6; ++kc) {
    const int k0 = kc * 32;
    {
      int rb = (w << 4) + (lane >> 2);
      int colb = k0 + ((((lane & 3) + (rb >> 2)) & 3) << 3);
      async16(mcB + (size_t)(m0 + rb) * NC + colb, At + (size_t)(w << 4) * 32);
    }
#pragma unroll
    for (int i = 0; i < 4; ++i) {
      int r = i * 64 + (w << 4) + (lane >> 2);
      int col = k0 + ((((lane & 3) + (r >> 2)) & 3) << 3);
      async16(vB + (size_t)(s0 + r) * NC3 + col, Bt + (size_t)(i * 64 + (w << 4)) * 32);
    }
    __syncthreads();
    f16x8 af[4];
#pragma unroll
    for (int mt = 0; mt < 4; ++mt) {
      int m = mt * 16 + l16;
      int p = (quad - (m >> 2)) & 3;
      af[mt] = *(const f16x8*)(At + m * 32 + p * 8);
    }
#pragma unroll
    for (int nt = 0; nt < 4; ++nt) {
      int n = w * 64 + nt * 16 + l16;
      int p = (quad - (n >> 2)) & 3;
      f16x8 bf = *(const f16x8*)(Bt + n * 32 + p * 8);
#pragma unroll
      for (int mt = 0; mt < 4; ++mt) acc[mt][nt] = MFMA(af[mt], bf, acc[mt][nt]);
    }
    __syncthreads();
  }
#pragma unroll
  for (int mt = 0; mt < 4; ++mt)
#pragma unroll
    for (int r = 0; r < 4; ++r) {
      int cog = m0 + mt * 16 + quad * 4 + r;
      float* o = out + ((size_t)b * NC + cog) * NS + s0 + w * 64;
#pragma unroll
      for (int nt = 0; nt < 4; ++nt) o[nt * 16 + l16] = acc[mt][nt][r];
    }
}

// ---------------------------------------------------------------------------
extern "C" void kernel_launch(void* const* d_in, const int* in_sizes, int n_in,
                              void* d_out, int out_size, void* d_ws, size_t ws_size,
                              hipStream_t stream) {
  const float* x   = (const float*)d_in[0];
  const float* cn  = (const float*)d_in[1];
  const float* w1  = (const float*)d_in[2];
  const float* w3  = (const float*)d_in[3];
  const float* wq  = (const float*)d_in[4];
  const float* wdw = (const float*)d_in[5];
  const float* wpj = (const float*)d_in[6];
  const float* tmp = (const float*)d_in[7];
  float* out = (float*)d_out;
  char* ws = (char*)d_ws;

  f16* x16    = (f16*)(ws + OFF_X16);
  f16* cn16   = (f16*)(ws + OFF_CN16);
  f16* qkv1p  = (f16*)(ws + OFF_CN16);   // overlay: cn16 dead after kernel A
  f16* cn1    = (f16*)(ws + OFF_CN1);
  f16* cnf    = (f16*)(ws + OFF_CNF);
  f16* qkvd   = (f16*)(ws + OFF_QKVD);
  float* norms = (float*)(ws + OFF_NORMS);
  float* G1    = (float*)(ws + OFF_G1);
  float* G2    = (float*)(ws + OFF_G2);
  f16* zpad   = (f16*)(ws + OFF_ZPAD);
  float* attn  = (float*)(ws + OFF_ATTN);
  f16* w116   = (f16*)(ws + OFF_W116);
  f16* wq16   = (f16*)(ws + OFF_WQ16);
  f16* w3p    = (f16*)(ws + OFF_W3P);
  f16* mcomb  = (f16*)(ws + OFF_MCOMB);
  f16* wdwT   = (f16*)(ws + OFF_WDWT);
  float* G1p   = (float*)(ws + OFF_G1P);   // overlays dead cn1
  float* G2p   = (float*)(ws + OFF_G2P);
  float* npart = (float*)(ws + OFF_NPART);

  // zero page for conv3 edge lanes (ws is re-poisoned before every launch)
  hipMemsetAsync(ws + OFF_ZPAD, 0, 1024, stream);

  k_wcast<<<1893, 256, 0, stream>>>(w1, wq, w3, wdw, w116, wq16, w3p, wdwT);
  k_cast_t<<<dim3(256, 3, 16), 256, 0, stream>>>(x, cn, x16, cn16);
  k_gemm_act<<<dim3(64, 3, 8), 256, 0, stream>>>(cn16, w116, cn1);
  k_conv3<<<1536, 256, 0, stream>>>(cn1, w3p, cnf, zpad);
  for (int p = 0; p < 3; ++p) {
    k_gemm_act<<<dim3(64, 3, 8), 256, 0, stream>>>(x16, wq16 + p * 36864, qkv1p);
    k_dw<<<12288, 256, 0, stream>>>(qkv1p, wdwT, qkvd, p);
  }
  k_e2<<<1024, 64, 0, stream>>>(qkvd, cnf, G1p, G2p, npart);
  k_e1b<<<24, 256, 0, stream>>>(npart, norms);
  k_e2b<<<1152, 256, 0, stream>>>(G1p, G2p, G1, G2);
  k_f1<<<32, 64, 0, stream>>>(G1, G2, norms, tmp, attn);
  k_f2<<<1152, 256, 0, stream>>>(attn, wpj, mcomb);
  k_gemm_out<<<dim3(64, 3, 8), 256, 0, stream>>>(mcomb, qkvd, out);

  (void)in_sizes; (void)n_in; (void)out_size; (void)ws_size;
}

// Round 3
// 672.811 us; speedup vs baseline: 1.1133x; 1.0482x over previous
//
#include <hip/hip_runtime.h>
#include <hip/hip_bf16.h>

typedef _Float16 f16;
typedef _Float16 f16x4 __attribute__((ext_vector_type(4)));
typedef _Float16 f16x8 __attribute__((ext_vector_type(8)));
typedef float f32x4 __attribute__((ext_vector_type(4)));

#define NB 8
#define NC 192
#define NC3 576
#define NS 16384
#define NHD 4

// ---- workspace offsets (bytes). total ~355 MB ----
#define OFF_X16   (0ll)
#define OFF_CN16  (50331648ll)     // reused as qkv1 part buffer
#define OFF_CN1   (100663296ll)
#define OFF_CNF   (150994944ll)
#define OFF_QKVD  (201326592ll)
#define OFF_NORMS (352321536ll)
#define OFF_G1    (352346112ll)
#define OFF_G2    (352641024ll)
#define OFF_ZPAD  (352935936ll)
#define OFF_ATTN  (352936960ll)
#define OFF_W116  (353231872ll)
#define OFF_WQ16  (353305600ll)
#define OFF_W3P   (353526784ll)
#define OFF_MCOMB (354190336ll)
#define OFF_WDWT  (354780160ll)
// E-stage partials overlay the dead cn1 buffer [OFF_CN1, OFF_CN1+50MB)
#define OFF_G1P   (100663296ll)               // 8*4*32*2304*4 = 9437184
#define OFF_G2P   (110100480ll)               // 9437184
#define OFF_NPART (119537664ll)               // 8*32*192*4*4 = 786432

__device__ __forceinline__ void async16(const void* g, void* l) {
  __builtin_amdgcn_global_load_lds(
      (const __attribute__((address_space(1))) unsigned int*)g,
      (__attribute__((address_space(3))) unsigned int*)l, 16, 0, 0);
}
#define MFMA(a,b,c) __builtin_amdgcn_mfma_f32_16x16x32_f16((a),(b),(c),0,0,0)

// ---------------------------------------------------------------------------
// P2: cast/pack all weights to f16. w3 repacked [tap][co][ci]; wdw repacked+cast
// to wdwT[tap][gc] (f16) so k_dw can load 8 channels' weights as one 16B read.
__global__ void k_wcast(const float* __restrict__ w1, const float* __restrict__ wq,
                        const float* __restrict__ w3, const float* __restrict__ wdw,
                        f16* __restrict__ w1o, f16* __restrict__ wqo,
                        f16* __restrict__ w3p, f16* __restrict__ wdwT)
{
  int idx = blockIdx.x * 256 + threadIdx.x;              // 484416 total
  if (idx < 36864) {
    w1o[idx] = (f16)w1[idx];
  } else if (idx < 147456) {
    int i = idx - 36864;
    wqo[i] = (f16)wq[i];
  } else if (idx < 479232) {
    int i = idx - 147456;
    int tap = i / 36864;
    int rem = i % 36864;                                 // co*192+ci
    w3p[i] = (f16)w3[(size_t)rem * 9 + tap];
  } else if (idx < 484416) {
    int i = idx - 479232;                                // 5184 = 9*576
    int tap = i / 576;
    int gc = i % 576;
    wdwT[i] = (f16)wdw[(size_t)gc * 9 + tap];
  }
}

// ---------------------------------------------------------------------------
// Fused transpose-cast GEMM: out[b][s][co] = sum_ci actf[b][ci][s] * wt[co][ci].
// actf is fp32 CHANNEL-major (the original input layout) — each wave loads a
// 1KB-contiguous row chunk, casts in-reg, and ds_writes the rotation-swizzled
// At tile (same layout the MFMA fragment reads expect). Replaces k_cast_t +
// k_gemm_act. M=256 s, N=64 co, K=192 (6x32).
__global__ __launch_bounds__(256, 2)
void k_gemm_tc(const float* __restrict__ actf, const f16* __restrict__ wt,
               f16* __restrict__ out)
{
  __shared__ f16 At[256 * 32];
  __shared__ f16 Bt[64 * 32];
  const int tid = threadIdx.x;
  // flat 1536 grid, XCD-chunked bijective swizzle (1536 % 8 == 0):
  // consecutive rem on one XCD -> the 3 n-blocks sharing an A-panel co-reside.
  const int bid = blockIdx.x;                      // 0..1535
  const int b = bid & 7;
  const int rem = bid >> 3;                        // 0..191 = stile*3 + nblk
  const int s0 = (rem / 3) * 256;
  const int n0 = (rem % 3) * 64;
  const int w = tid >> 6, lane = tid & 63, quad = lane >> 4, l16 = lane & 15;
  const int sb = lane;                             // 4-s group (0..63)
  const int cb = w;                                // 8-ci chunk (0..3)
  const float* actB = actf + ((size_t)b * NC) * NS + s0 + 4 * sb;

  const f32x4 Z = {0.f, 0.f, 0.f, 0.f};
  f32x4 acc[4][4];
#pragma unroll
  for (int i = 0; i < 4; ++i)
#pragma unroll
    for (int j = 0; j < 4; ++j) acc[i][j] = Z;

  for (int kc = 0; kc < 6; ++kc) {
    const int k0 = kc * 32;
    // ---- load 8 fp32 rows (ci = k0+cb*8 .. +7), 4 s each, coalesced ----
    const float* ap = actB + (size_t)(k0 + cb * 8) * NS;
    f32x4 r[8];
#pragma unroll
    for (int rr = 0; rr < 8; ++rr) r[rr] = *(const f32x4*)(ap + (size_t)rr * NS);
    __syncthreads();                 // prev iteration's fragment reads done
    // ---- Bt stage (f16 weights, async16, rotation swizzle) ----
    {
      int rb = (w << 4) + (lane >> 2);
      int colb = k0 + ((((lane & 3) + (rb >> 2)) & 3) << 3);
      async16(wt + (size_t)(n0 + rb) * NC + colb, Bt + (size_t)(w << 4) * 32);
    }
    // ---- At: cast + transposed write. At[s][cp] holds global chunk cb,
    //      cp = (cb - (s>>2))&3  <=>  read rule chunk(p) = (p+(m>>2))&3 ----
    const int cp = (cb - sb) & 3;
#pragma unroll
    for (int j = 0; j < 4; ++j) {
      f16x8 o;
#pragma unroll
      for (int rr = 0; rr < 8; ++rr) o[rr] = (f16)r[rr][j];
      *(f16x8*)(At + (4 * sb + j) * 32 + cp * 8) = o;
    }
    __syncthreads();

    f16x8 bf[4];
#pragma unroll
    for (int nt = 0; nt < 4; ++nt) {
      int n = nt * 16 + l16;
      int p = (quad - (n >> 2)) & 3;
      bf[nt] = *(const f16x8*)(Bt + n * 32 + p * 8);
    }
#pragma unroll
    for (int mt = 0; mt < 4; ++mt) {
      int m = w * 64 + mt * 16 + l16;
      int p = (quad - (m >> 2)) & 3;
      f16x8 af = *(const f16x8*)(At + m * 32 + p * 8);
#pragma unroll
      for (int nt = 0; nt < 4; ++nt) acc[mt][nt] = MFMA(af, bf[nt], acc[mt][nt]);
    }
  }
#pragma unroll
  for (int mt = 0; mt < 4; ++mt)
#pragma unroll
    for (int r = 0; r < 4; ++r) {
      int sg = s0 + w * 64 + mt * 16 + quad * 4 + r;
      f16* o = out + ((size_t)b * NS + sg) * NC + n0;
#pragma unroll
      for (int nt = 0; nt < 4; ++nt) o[nt * 16 + l16] = (f16)acc[mt][nt][r];
    }
}

// ---------------------------------------------------------------------------
// conv3x3 implicit GEMM, halo-staged: per block, 2 output image rows (256 s),
// 64 co. Per K-chunk of 32 ci: stage 4-row halo (y0-1..y0+2) x [pad|128|pad]
// once; all 9 taps read it at LDS offsets. Taps' B staged in 2 groups (5+4).
__global__ __launch_bounds__(256, 2)
void k_conv3(const f16* __restrict__ act, const f16* __restrict__ w3p,
             f16* __restrict__ out, const f16* __restrict__ zpad)
{
  __shared__ f16 At[4 * 130 * 32];   // 33280 B: [row 0..3][xp 0..129][32ch] swizzled
  __shared__ f16 Bt[5 * 64 * 32];    // 20480 B: [tapslot][co][32ch] swizzled
  const int tid = threadIdx.x;
  // XCD-chunked bijective swizzle (1536 % 8 == 0)
  const int bid = blockIdx.x;                      // 0..1535
  const int swz = (bid & 7) * 192 + (bid >> 3);
  const int b = swz / 192;
  const int rem = swz % 192;                       // stile*3 + nblk
  const int stile = rem / 3;
  const int nblk = rem % 3;
  const int y0 = stile * 2;
  const int s0 = stile * 256;
  const int n0 = nblk * 64;
  const int w = tid >> 6, lane = tid & 63, quad = lane >> 4, l16 = lane & 15;
  const f16* actB = act + (size_t)b * NS * NC;

  // zero the xp=0 / xp=129 pad columns once (staging never writes them)
  {
    int pos = tid >> 5, ch = tid & 31;             // 8 pad positions x 32 ch
    At[((pos >> 1) * 130 + ((pos & 1) ? 129 : 0)) * 32 + ch] = (f16)0.f;
  }

  const f32x4 Z = {0.f, 0.f, 0.f, 0.f};
  f32x4 acc[4][4];
#pragma unroll
  for (int i = 0; i < 4; ++i)
#pragma unroll
    for (int j = 0; j < 4; ++j) acc[i][j] = Z;

  const int yrow = y0 - 1 + w;                     // wave-uniform halo row
  const bool rowok = ((unsigned)yrow < 128u);
  const f16* arow = actB + (size_t)(yrow * 128) * NC;

  for (int kc = 0; kc < 6; ++kc) {
    const int k0 = kc * 32;
    // ---- stage At: wave w stages halo row w (xp 1..128), swizzled source ----
#pragma unroll
    for (int i = 0; i < 8; ++i) {
      int x = i * 16 + (lane >> 2);
      int rs = w * 130 + 1 + x;                    // staged position index
      int gsrc = ((lane & 3) + (rs >> 2)) & 3;
      const f16* g = rowok ? (arow + (size_t)x * NC + k0 + gsrc * 8)
                           : (const f16*)zpad;
      async16(g, At + (w * 130 + 1) * 32 + i * 512);
    }
    // ---- stage Bt taps 0..4 ----
#pragma unroll
    for (int tp = 0; tp < 5; ++tp) {
      int co = (w << 4) + (lane >> 2);
      int gsrc = ((lane & 3) + (co >> 2)) & 3;
      async16(w3p + (size_t)tp * NC * NC + (size_t)(n0 + co) * NC + k0 + gsrc * 8,
              Bt + (tp * 64 + (w << 4)) * 32);
    }
    __syncthreads();
    // ---- compute taps 0..4 ----
#pragma unroll
    for (int tp = 0; tp < 5; ++tp) {
      const int dy = tp / 3 - 1, dx = tp % 3 - 1;
      f16x8 bf[4];
#pragma unroll
      for (int nt = 0; nt < 4; ++nt) {
        int n = nt * 16 + l16;
        int p = (quad - (n >> 2)) & 3;
        bf[nt] = *(const f16x8*)(Bt + (tp * 64 + n) * 32 + p * 8);
      }
#pragma unroll
      for (int mt = 0; mt < 4; ++mt) {
        int m = (w << 6) + mt * 16 + l16;
        int rr = ((m >> 7) + 1 + dy) * 130 + (m & 127) + 1 + dx;
        int p = (quad - (rr >> 2)) & 3;
        f16x8 af = *(const f16x8*)(At + rr * 32 + p * 8);
#pragma unroll
        for (int nt = 0; nt < 4; ++nt) acc[mt][nt] = MFMA(af, bf[nt], acc[mt][nt]);
      }
    }
    __syncthreads();
    // ---- stage Bt taps 5..8 into slots 0..3 ----
#pragma unroll
    for (int tp = 0; tp < 4; ++tp) {
      int co = (w << 4) + (lane >> 2);
      int gsrc = ((lane & 3) + (co >> 2)) & 3;
      async16(w3p + (size_t)(tp + 5) * NC * NC + (size_t)(n0 + co) * NC + k0 + gsrc * 8,
              Bt + (tp * 64 + (w << 4)) * 32);
    }
    __syncthreads();
    // ---- compute taps 5..8 ----
#pragma unroll
    for (int tp = 0; tp < 4; ++tp) {
      const int tap = tp + 5;
      const int dy = tap / 3 - 1, dx = tap % 3 - 1;
      f16x8 bf[4];
#pragma unroll
      for (int nt = 0; nt < 4; ++nt) {
        int n = nt * 16 + l16;
        int p = (quad - (n >> 2)) & 3;
        bf[nt] = *(const f16x8*)(Bt + (tp * 64 + n) * 32 + p * 8);
      }
#pragma unroll
      for (int mt = 0; mt < 4; ++mt) {
        int m = (w << 6) + mt * 16 + l16;
        int rr = ((m >> 7) + 1 + dy) * 130 + (m & 127) + 1 + dx;
        int p = (quad - (rr >> 2)) & 3;
        f16x8 af = *(const f16x8*)(At + rr * 32 + p * 8);
#pragma unroll
        for (int nt = 0; nt < 4; ++nt) acc[mt][nt] = MFMA(af, bf[nt], acc[mt][nt]);
      }
    }
    __syncthreads();
  }
#pragma unroll
  for (int mt = 0; mt < 4; ++mt)
#pragma unroll
    for (int r = 0; r < 4; ++r) {
      int sg = s0 + (w << 6) + mt * 16 + quad * 4 + r;
      f16* o = out + ((size_t)b * NS + sg) * NC + n0;
#pragma unroll
      for (int nt = 0; nt < 4; ++nt) o[nt * 16 + l16] = (f16)acc[mt][nt][r];
    }
}

// ---------------------------------------------------------------------------
// depthwise 3x3, 8-channel vectorized: one thread = 8 consecutive channels of one s.
__global__ __launch_bounds__(256)
void k_dw(const f16* __restrict__ in, const f16* __restrict__ wdwT,
          f16* __restrict__ out, int part)
{
  int idx = blockIdx.x * 256 + threadIdx.x;   // exact 3145728 = 8*16384*24
  int cg = idx % 24;
  int s = (idx / 24) % NS;
  int b = idx / (24 * NS);
  int x = s & 127, y = s >> 7;
  const f16* ip = in + ((size_t)b * NS + s) * NC + cg * 8;
  const f16* wp = wdwT + part * NC + cg * 8;
  float a[8] = {0.f, 0.f, 0.f, 0.f, 0.f, 0.f, 0.f, 0.f};
#pragma unroll
  for (int t = 0; t < 9; ++t) {
    int dy = t / 3 - 1, dx = t % 3 - 1;
    if (((unsigned)(x + dx) < 128u) && ((unsigned)(y + dy) < 128u)) {
      f16x8 v = *(const f16x8*)(ip + (dy * 128 + dx) * NC);
      f16x8 wv = *(const f16x8*)(wp + t * NC3);
#pragma unroll
      for (int j = 0; j < 8; ++j) a[j] += (float)wv[j] * (float)v[j];
    }
  }
  f16x8 o;
#pragma unroll
  for (int j = 0; j < 8; ++j) o[j] = (f16)a[j];
  *(f16x8*)(out + ((size_t)b * NS + s) * NC3 + part * NC + cg * 8) = o;
}

// ---------------------------------------------------------------------------
// E2 (fused with E1): per (b,h,split of 512 s): G1p = Q*K^T, G2p = CN*K^T partials
// via LDS-transpose + MFMA; per-channel stats (q2,k2,cn2,qc) from the same
// fragments, shfl-reduced across quads. NO ATOMICS.
__global__ __launch_bounds__(64)
void k_e2(const f16* __restrict__ qkvd, const f16* __restrict__ cnf,
          float* __restrict__ G1p, float* __restrict__ G2p,
          float* __restrict__ npart)
{
  __shared__ f16 qT[48 * 72];
  __shared__ f16 kT[48 * 72];
  __shared__ f16 cT[48 * 72];
  int blk = blockIdx.x;               // b(8) x h(4) x split(32)
  int split = blk & 31;
  int h = (blk >> 5) & 3;
  int b = blk >> 7;
  int lane = threadIdx.x, quad = lane >> 4, l16 = lane & 15;
  const f32x4 Z = {0.f, 0.f, 0.f, 0.f};
  f32x4 g1[3][3], g2[3][3];
#pragma unroll
  for (int i = 0; i < 3; ++i)
#pragma unroll
    for (int j = 0; j < 3; ++j) { g1[i][j] = Z; g2[i][j] = Z; }
  float q2[3] = {0.f, 0.f, 0.f}, k2[3] = {0.f, 0.f, 0.f};
  float cn2[3] = {0.f, 0.f, 0.f}, qc[3] = {0.f, 0.f, 0.f};

  int sBase = split * 512;
  for (int chunk = 0; chunk < 8; ++chunk) {
    int sb = sBase + chunk * 64;
    const f16* qrow = qkvd + ((size_t)b * NS + sb + lane) * NC3 + h * 48;
    const f16* crow = cnf + ((size_t)b * NS + sb + lane) * NC + h * 48;
    f16x8 qv[6], kv[6], nv[6];
#pragma unroll
    for (int i = 0; i < 6; ++i) {
      qv[i] = *(const f16x8*)(qrow + i * 8);
      kv[i] = *(const f16x8*)(qrow + 192 + i * 8);
      nv[i] = *(const f16x8*)(crow + i * 8);
    }
    __syncthreads();                 // previous iter's frag reads done
#pragma unroll
    for (int i = 0; i < 6; ++i)
#pragma unroll
      for (int j = 0; j < 8; ++j) {
        int c = i * 8 + j;
        qT[c * 72 + lane] = qv[i][j];
        kT[c * 72 + lane] = kv[i][j];
        cT[c * 72 + lane] = nv[i][j];
      }
    __syncthreads();
#pragma unroll
    for (int kk = 0; kk < 2; ++kk) {
      int ko = kk * 32 + quad * 8;
      f16x8 bfr[3];
#pragma unroll
      for (int dt = 0; dt < 3; ++dt) {
        bfr[dt] = *(const f16x8*)(kT + (dt * 16 + l16) * 72 + ko);
#pragma unroll
        for (int j = 0; j < 8; ++j) { float kf = (float)bfr[dt][j]; k2[dt] += kf * kf; }
      }
#pragma unroll
      for (int ct = 0; ct < 3; ++ct) {
        f16x8 aq = *(const f16x8*)(qT + (ct * 16 + l16) * 72 + ko);
        f16x8 an = *(const f16x8*)(cT + (ct * 16 + l16) * 72 + ko);
#pragma unroll
        for (int j = 0; j < 8; ++j) {
          float qf = (float)aq[j], nf = (float)an[j];
          q2[ct] += qf * qf; cn2[ct] += nf * nf; qc[ct] += qf * nf;
        }
#pragma unroll
        for (int dt = 0; dt < 3; ++dt) {
          g1[ct][dt] = MFMA(aq, bfr[dt], g1[ct][dt]);
          g2[ct][dt] = MFMA(an, bfr[dt], g2[ct][dt]);
        }
      }
    }
  }
  // G partial write (coalesced, no atomics)
  size_t gbase = ((size_t)((b * NHD + h) * 32 + split)) * 2304;
#pragma unroll
  for (int ct = 0; ct < 3; ++ct)
#pragma unroll
    for (int dt = 0; dt < 3; ++dt)
#pragma unroll
      for (int r = 0; r < 4; ++r) {
        int c = ct * 16 + quad * 4 + r;
        int d = dt * 16 + l16;
        G1p[gbase + c * 48 + d] = g1[ct][dt][r];
        G2p[gbase + c * 48 + d] = g2[ct][dt][r];
      }
  // stats: reduce across quads (lanes l16, l16+16, l16+32, l16+48)
#pragma unroll
  for (int t = 0; t < 3; ++t) {
    q2[t] += __shfl_xor(q2[t], 16, 64);  q2[t] += __shfl_xor(q2[t], 32, 64);
    k2[t] += __shfl_xor(k2[t], 16, 64);  k2[t] += __shfl_xor(k2[t], 32, 64);
    cn2[t] += __shfl_xor(cn2[t], 16, 64); cn2[t] += __shfl_xor(cn2[t], 32, 64);
    qc[t] += __shfl_xor(qc[t], 16, 64);  qc[t] += __shfl_xor(qc[t], 32, 64);
  }
  if (lane < 16) {
#pragma unroll
    for (int ct = 0; ct < 3; ++ct) {
      int c = h * 48 + ct * 16 + lane;
      float* np = npart + (((size_t)(b * 32 + split)) * NC + c) * 4;
      np[0] = q2[ct]; np[1] = k2[ct]; np[2] = cn2[ct]; np[3] = qc[ct];
    }
  }
}

// ---------------------------------------------------------------------------
// E1b: norms[b][c][4] = sum over 32 splits of npart. 6144 threads, coalesced.
__global__ void k_e1b(const float* __restrict__ npart, float* __restrict__ norms)
{
  int idx = blockIdx.x * 256 + threadIdx.x;    // 6144
  int b = idx / 768;
  int cs = idx % 768;                          // c*4 + stat
  const float* p = npart + (size_t)b * 32 * 768 + cs;
  float s = 0.f;
#pragma unroll
  for (int sp = 0; sp < 32; ++sp) s += p[sp * 768];
  norms[idx] = s;
}

// ---------------------------------------------------------------------------
// E2b: G[bh][c][d] = sum over 32 splits of partials. 294912 threads, coalesced.
__global__ void k_e2b(const float* __restrict__ G1p, const float* __restrict__ G2p,
                      float* __restrict__ G1, float* __restrict__ G2)
{
  int idx = blockIdx.x * 256 + threadIdx.x;    // 294912
  int bh = idx / 2304;
  int cd = idx % 2304;
  const float* p1 = G1p + ((size_t)bh * 32) * 2304 + cd;
  const float* p2 = G2p + ((size_t)bh * 32) * 2304 + cd;
  float s1 = 0.f, s2 = 0.f;
#pragma unroll
  for (int sp = 0; sp < 32; ++sp) { s1 += p1[sp * 2304]; s2 += p2[sp * 2304]; }
  G1[idx] = s1;
  G2[idx] = s2;
}

// ---------------------------------------------------------------------------
// F1: logits + softmax -> attn[b][h][c][d] (fp32)
__global__ __launch_bounds__(64)
void k_f1(const float* __restrict__ G1, const float* __restrict__ G2,
          const float* __restrict__ norms, const float* __restrict__ temp,
          float* __restrict__ attn)
{
  __shared__ float S[48 * 48];
  int h = blockIdx.x & 3, b = blockIdx.x >> 2;
  int t = threadIdx.x;
  float T = temp[h];
  const float EPS = 1e-12f;
#pragma unroll
  for (int i = 0; i < 36; ++i) {
    int idx = i * 64 + t;
    int c = idx / 48, d = idx % 48;
    const float* np = norms + ((size_t)b * NC + h * 48 + c) * 4;
    float q2 = np[0], cn2 = np[2], qc = np[3];
    float nq = fmaxf(sqrtf(q2), EPS);
    float ncn = fmaxf(sqrtf(cn2), EPS);
    float k2 = norms[((size_t)b * NC + h * 48 + d) * 4 + 1];
    float nk = fmaxf(sqrtf(k2), EPS);
    float ss = q2 / (nq * nq) + 2.f * qc / (nq * ncn) + cn2 / (ncn * ncn);
    float nsum = fmaxf(sqrtf(fmaxf(ss, 0.f)), EPS);
    size_t go = (((size_t)(b * NHD + h) * 48 + c) * 48 + d);
    S[idx] = (G1[go] / nq + G2[go] / ncn) / (nsum * nk) * T;
  }
  __syncthreads();
  if (t < 48) {
    float mx = -1e30f;
    for (int d = 0; d < 48; ++d) mx = fmaxf(mx, S[t * 48 + d]);
    float sum = 0.f;
    for (int d = 0; d < 48; ++d) { float e = expf(S[t * 48 + d] - mx); S[t * 48 + d] = e; sum += e; }
    float inv = 1.f / sum;
    float* ap = attn + (((size_t)(b * NHD + h) * 48 + t) * 48);
    for (int d = 0; d < 48; ++d) ap[d] = S[t * 48 + d] * inv;
  }
}

// ---------------------------------------------------------------------------
// F2: Mcomb[b][co][dg] = sum_cl projw[co][h*48+cl] * attn[b][h][cl][dg%48]  (f16 out)
__global__ void k_f2(const float* __restrict__ attn, const float* __restrict__ projw,
                     f16* __restrict__ mcomb)
{
  int idx = blockIdx.x * 256 + threadIdx.x;   // 294912 exact
  int dg = idx % NC;
  int co = (idx / NC) % NC;
  int b = idx / (NC * NC);
  int h = dg / 48, dl = dg % 48;
  const float* pw = projw + (size_t)co * NC + h * 48;
  const float* at = attn + ((size_t)(b * NHD + h) * 48) * 48 + dl;
  float a = 0.f;
#pragma unroll
  for (int cl = 0; cl < 48; ++cl) a += pw[cl] * at[cl * 48];
  mcomb[idx] = (f16)a;
}

// ---------------------------------------------------------------------------
// G: out[b][co][s] = sum_dg mcomb[b][co][dg] * v[b][s][dg], fp32 out
__global__ __launch_bounds__(256, 2)
void k_gemm_out(const f16* __restrict__ mcomb, const f16* __restrict__ qkvd,
                float* __restrict__ out)
{
  __shared__ f16 At[64 * 32];
  __shared__ f16 Bt[256 * 32];
  const int tid = threadIdx.x;
  const int b = blockIdx.z;
  const int s0 = blockIdx.x * 256;
  const int m0 = blockIdx.y * 64;
  const int w = tid >> 6, lane = tid & 63, quad = lane >> 4, l16 = lane & 15;
  const f16* mcB = mcomb + (size_t)b * NC * NC;
  const f16* vB = qkvd + (size_t)b * NS * NC3 + 384;

  const f32x4 Z = {0.f, 0.f, 0.f, 0.f};
  f32x4 acc[4][4];
#pragma unroll
  for (int i = 0; i < 4; ++i)
#pragma unroll
    for (int j = 0; j < 4; ++j) acc[i][j] = Z;

  for (int kc = 0; kc < 6; ++kc) {
    const int k0 = kc * 32;
    {
      int rb = (w << 4) + (lane >> 2);
      int colb = k0 + ((((lane & 3) + (rb >> 2)) & 3) << 3);
      async16(mcB + (size_t)(m0 + rb) * NC + colb, At + (size_t)(w << 4) * 32);
    }
#pragma unroll
    for (int i = 0; i < 4; ++i) {
      int r = i * 64 + (w << 4) + (lane >> 2);
      int col = k0 + ((((lane & 3) + (r >> 2)) & 3) << 3);
      async16(vB + (size_t)(s0 + r) * NC3 + col, Bt + (size_t)(i * 64 + (w << 4)) * 32);
    }
    __syncthreads();
    f16x8 af[4];
#pragma unroll
    for (int mt = 0; mt < 4; ++mt) {
      int m = mt * 16 + l16;
      int p = (quad - (m >> 2)) & 3;
      af[mt] = *(const f16x8*)(At + m * 32 + p * 8);
    }
#pragma unroll
    for (int nt = 0; nt < 4; ++nt) {
      int n = w * 64 + nt * 16 + l16;
      int p = (quad - (n >> 2)) & 3;
      f16x8 bf = *(const f16x8*)(Bt + n * 32 + p * 8);
#pragma unroll
      for (int mt = 0; mt < 4; ++mt) acc[mt][nt] = MFMA(af[mt], bf, acc[mt][nt]);
    }
    __syncthreads();
  }
#pragma unroll
  for (int mt = 0; mt < 4; ++mt)
#pragma unroll
    for (int r = 0; r < 4; ++r) {
      int cog = m0 + mt * 16 + quad * 4 + r;
      float* o = out + ((size_t)b * NC + cog) * NS + s0 + w * 64;
#pragma unroll
      for (int nt = 0; nt < 4; ++nt) o[nt * 16 + l16] = acc[mt][nt][r];
    }
}

// ---------------------------------------------------------------------------
extern "C" void kernel_launch(void* const* d_in, const int* in_sizes, int n_in,
                              void* d_out, int out_size, void* d_ws, size_t ws_size,
                              hipStream_t stream) {
  const float* x   = (const float*)d_in[0];
  const float* cn  = (const float*)d_in[1];
  const float* w1  = (const float*)d_in[2];
  const float* w3  = (const float*)d_in[3];
  const float* wq  = (const float*)d_in[4];
  const float* wdw = (const float*)d_in[5];
  const float* wpj = (const float*)d_in[6];
  const float* tmp = (const float*)d_in[7];
  float* out = (float*)d_out;
  char* ws = (char*)d_ws;

  f16* qkv1p  = (f16*)(ws + OFF_CN16);
  f16* cn1    = (f16*)(ws + OFF_CN1);
  f16* cnf    = (f16*)(ws + OFF_CNF);
  f16* qkvd   = (f16*)(ws + OFF_QKVD);
  float* norms = (float*)(ws + OFF_NORMS);
  float* G1    = (float*)(ws + OFF_G1);
  float* G2    = (float*)(ws + OFF_G2);
  f16* zpad   = (f16*)(ws + OFF_ZPAD);
  float* attn  = (float*)(ws + OFF_ATTN);
  f16* w116   = (f16*)(ws + OFF_W116);
  f16* wq16   = (f16*)(ws + OFF_WQ16);
  f16* w3p    = (f16*)(ws + OFF_W3P);
  f16* mcomb  = (f16*)(ws + OFF_MCOMB);
  f16* wdwT   = (f16*)(ws + OFF_WDWT);
  float* G1p   = (float*)(ws + OFF_G1P);   // overlays dead cn1
  float* G2p   = (float*)(ws + OFF_G2P);
  float* npart = (float*)(ws + OFF_NPART);

  // zero page for conv3 edge lanes (ws is re-poisoned before every launch)
  hipMemsetAsync(ws + OFF_ZPAD, 0, 1024, stream);

  k_wcast<<<1893, 256, 0, stream>>>(w1, wq, w3, wdw, w116, wq16, w3p, wdwT);
  k_gemm_tc<<<1536, 256, 0, stream>>>(cn, w116, cn1);
  k_conv3<<<1536, 256, 0, stream>>>(cn1, w3p, cnf, zpad);
  for (int p = 0; p < 3; ++p) {
    k_gemm_tc<<<1536, 256, 0, stream>>>(x, wq16 + p * 36864, qkv1p);
    k_dw<<<12288, 256, 0, stream>>>(qkv1p, wdwT, qkvd, p);
  }
  k_e2<<<1024, 64, 0, stream>>>(qkvd, cnf, G1p, G2p, npart);
  k_e1b<<<24, 256, 0, stream>>>(npart, norms);
  k_e2b<<<1152, 256, 0, stream>>>(G1p, G2p, G1, G2);
  k_f1<<<32, 64, 0, stream>>>(G1, G2, norms, tmp, attn);
  k_f2<<<1152, 256, 0, stream>>>(attn, wpj, mcomb);
  k_gemm_out<<<dim3(64, 3, 8), 256, 0, stream>>>(mcomb, qkvd, out);

  (void)in_sizes; (void)n_in; (void)out_size; (void)ws_size;
}